// Round 2
// baseline (2654.340 us; speedup 1.0000x reference)
//
#include <hip/hip_runtime.h>
#include <math.h>

#define BN_EPS 1e-5f

namespace {

constexpr int Bb = 32;   // batch
constexpr int Cc = 512;  // channels
constexpr int Nn = 1024; // spatial (H*W)
constexpr int Ee = 1024; // embed

constexpr int BM  = 128;
constexpr int BNc = 128;
constexpr int BK  = 16;
constexpr int LDT = BM + 4;  // 132 floats: 528B row stride, 16B-aligned

__global__ __launch_bounds__(256) void prep_st_kernel(
    const float* __restrict__ g, const float* __restrict__ be,
    const float* __restrict__ mn, const float* __restrict__ vr,
    float* __restrict__ s, float* __restrict__ t, int n) {
  int i = blockIdx.x * blockDim.x + threadIdx.x;
  if (i < n) {
    float inv = rsqrtf(vr[i] + BN_EPS);
    float sc = g[i] * inv;
    s[i] = sc;
    t[i] = be[i] - mn[i] * sc;
  }
}

__device__ __forceinline__ float4 bn4(float4 x, float4 s, float4 t) {
  float4 r;
  r.x = fmaxf(fmaf(x.x, s.x, t.x), 0.f);
  r.y = fmaxf(fmaf(x.y, s.y, t.y), 0.f);
  r.z = fmaxf(fmaf(x.z, s.z, t.z), 0.f);
  r.w = fmaxf(fmaf(x.w, s.w, t.w), 0.f);
  return r;
}

// NT GEMM: C[m][n] = alpha * sum_k A[m][k] * B[n][k]
// A row stride = K, B row stride = K, C row stride = Ncols.
// BNSIDE: 0 = none, 1 = BN+ReLU applied to A elements (per-k scale/shift),
//         2 = BN+ReLU applied to B elements.
template<int BNSIDE>
__global__ __launch_bounds__(256) void gemm_nt(
    const float* __restrict__ Ag, const float* __restrict__ Bg,
    float* __restrict__ Cg,
    int M, int Ncols, int K,
    long sA, long sB, long sC,
    const float* __restrict__ sArr, const float* __restrict__ tArr,
    float alpha) {
  __shared__ float As[BK][LDT];
  __shared__ float Bs[BK][LDT];

  const float* A = Ag + (long)blockIdx.z * sA;
  const float* B = Bg + (long)blockIdx.z * sB;
  float*       C = Cg + (long)blockIdx.z * sC;

  const int m0 = blockIdx.y * BM;
  const int n0 = blockIdx.x * BNc;
  const int t  = threadIdx.x;
  const int tx = t & 15;        // output col group
  const int ty = t >> 4;        // output row group
  const int r  = t >> 2;        // staging row 0..63
  const int q  = t & 3;         // staging k-quarter

  float acc[8][8] = {};

  const float* Arow0 = A + (long)(m0 + r) * K;
  const float* Arow1 = A + (long)(m0 + r + 64) * K;
  const float* Brow0 = B + (long)(n0 + r) * K;
  const float* Brow1 = B + (long)(n0 + r + 64) * K;

  for (int k0 = 0; k0 < K; k0 += BK) {
    float4 a0 = *(const float4*)(Arow0 + k0 + 4 * q);
    float4 a1 = *(const float4*)(Arow1 + k0 + 4 * q);
    float4 b0 = *(const float4*)(Brow0 + k0 + 4 * q);
    float4 b1 = *(const float4*)(Brow1 + k0 + 4 * q);
    if (BNSIDE) {
      float4 s4 = *(const float4*)(sArr + k0 + 4 * q);
      float4 t4 = *(const float4*)(tArr + k0 + 4 * q);
      if (BNSIDE == 1) { a0 = bn4(a0, s4, t4); a1 = bn4(a1, s4, t4); }
      else             { b0 = bn4(b0, s4, t4); b1 = bn4(b1, s4, t4); }
    }
    __syncthreads();  // previous tile fully consumed
    As[4*q+0][r]    = a0.x; As[4*q+1][r]    = a0.y;
    As[4*q+2][r]    = a0.z; As[4*q+3][r]    = a0.w;
    As[4*q+0][r+64] = a1.x; As[4*q+1][r+64] = a1.y;
    As[4*q+2][r+64] = a1.z; As[4*q+3][r+64] = a1.w;
    Bs[4*q+0][r]    = b0.x; Bs[4*q+1][r]    = b0.y;
    Bs[4*q+2][r]    = b0.z; Bs[4*q+3][r]    = b0.w;
    Bs[4*q+0][r+64] = b1.x; Bs[4*q+1][r+64] = b1.y;
    Bs[4*q+2][r+64] = b1.z; Bs[4*q+3][r+64] = b1.w;
    __syncthreads();  // tile ready
#pragma unroll
    for (int kk = 0; kk < BK; ++kk) {
      float av[8], bv[8];
      *(float4*)(av)     = *(const float4*)(&As[kk][ty * 8]);
      *(float4*)(av + 4) = *(const float4*)(&As[kk][ty * 8 + 4]);
      *(float4*)(bv)     = *(const float4*)(&Bs[kk][tx * 8]);
      *(float4*)(bv + 4) = *(const float4*)(&Bs[kk][tx * 8 + 4]);
#pragma unroll
      for (int i = 0; i < 8; ++i)
#pragma unroll
        for (int j = 0; j < 8; ++j)
          acc[i][j] = fmaf(av[i], bv[j], acc[i][j]);
    }
  }

#pragma unroll
  for (int i = 0; i < 8; ++i) {
    float* Crow = C + (long)(m0 + ty * 8 + i) * Ncols + (n0 + tx * 8);
    float4 c0, c1;
    c0.x = acc[i][0] * alpha; c0.y = acc[i][1] * alpha;
    c0.z = acc[i][2] * alpha; c0.w = acc[i][3] * alpha;
    c1.x = acc[i][4] * alpha; c1.y = acc[i][5] * alpha;
    c1.z = acc[i][6] * alpha; c1.w = acc[i][7] * alpha;
    *(float4*)(Crow)     = c0;
    *(float4*)(Crow + 4) = c1;
  }
}

// softmax over rows of 1024 f32, in place. One 256-thread block per row.
__global__ __launch_bounds__(256) void softmax_rows(float* __restrict__ S) {
  long row = blockIdx.x;
  float* p = S + row * 1024;
  int t = threadIdx.x;
  float4 v = *(float4*)(p + 4 * t);
  float mx = fmaxf(fmaxf(v.x, v.y), fmaxf(v.z, v.w));
#pragma unroll
  for (int i = 1; i < 64; i <<= 1) mx = fmaxf(mx, __shfl_xor(mx, i));
  __shared__ float redm[4];
  __shared__ float reds[4];
  int wave = t >> 6, lane = t & 63;
  if (lane == 0) redm[wave] = mx;
  __syncthreads();
  mx = fmaxf(fmaxf(redm[0], redm[1]), fmaxf(redm[2], redm[3]));
  float e0 = expf(v.x - mx), e1 = expf(v.y - mx);
  float e2 = expf(v.z - mx), e3 = expf(v.w - mx);
  float sum = (e0 + e1) + (e2 + e3);
#pragma unroll
  for (int i = 1; i < 64; i <<= 1) sum += __shfl_xor(sum, i);
  if (lane == 0) reds[wave] = sum;
  __syncthreads();
  sum = (reds[0] + reds[1]) + (reds[2] + reds[3]);
  float inv = 1.0f / sum;
  v.x = e0 * inv; v.y = e1 * inv; v.z = e2 * inv; v.w = e3 * inv;
  *(float4*)(p + 4 * t) = v;
}

}  // namespace

extern "C" void kernel_launch(void* const* d_in, const int* in_sizes, int n_in,
                              void* d_out, int out_size, void* d_ws, size_t ws_size,
                              hipStream_t stream) {
  const float* x  = (const float*)d_in[0];
  const float* qg = (const float*)d_in[1];
  const float* qb = (const float*)d_in[2];
  const float* qm = (const float*)d_in[3];
  const float* qv = (const float*)d_in[4];
  const float* kg = (const float*)d_in[5];
  const float* kb = (const float*)d_in[6];
  const float* km = (const float*)d_in[7];
  const float* kv = (const float*)d_in[8];
  const float* vg = (const float*)d_in[9];
  const float* vb = (const float*)d_in[10];
  const float* vm = (const float*)d_in[11];
  const float* vv = (const float*)d_in[12];
  const float* Wq = (const float*)d_in[13];
  const float* Wk = (const float*)d_in[14];
  const float* Wv = (const float*)d_in[15];
  const float* Wp = (const float*)d_in[16];

  // ---- workspace layout (adaptive batch chunking to fit ws_size) ----
  // header: 6 * 1024 f32 (BN scale/shift)  = 24 KiB, rounded to 64 KiB
  // per chunk of G batches:
  //   Q  [G][E][C]  G * 2 MiB   (reused as Ot [G][C][E] after scores)
  //   K  [G][E][C]  G * 2 MiB
  //   S  [G][E][E]  G * 4 MiB
  // Vt [B][C][E] lives in d_out (dead before final projection writes it).
  const size_t perBatch = (size_t)(Ee * Cc + Ee * Cc + Ee * Ee) * 4;  // 8 MiB
  int G = 32;
  while (G > 1 && 65536 + (size_t)G * perBatch > ws_size) G >>= 1;

  char* ws = (char*)d_ws;
  float* sq = (float*)ws;
  float* tq = sq + 1024;
  float* sk = tq + 1024;
  float* tk = sk + 1024;
  float* sv = tk + 1024;
  float* tv = sv + 1024;
  float* Q  = (float*)(ws + 65536);
  float* Kb = Q  + (size_t)G * Ee * Cc;
  float* S  = Kb + (size_t)G * Ee * Cc;
  float* Vt = (float*)d_out;   // [B][C][E]
  float* Ot = Q;               // reuse per chunk: [G][C][E]

  dim3 blk(256);

  prep_st_kernel<<<dim3(4), blk, 0, stream>>>(qg, qb, qm, qv, sq, tq, Nn);
  prep_st_kernel<<<dim3(4), blk, 0, stream>>>(kg, kb, km, kv, sk, tk, Nn);
  prep_st_kernel<<<dim3(4), blk, 0, stream>>>(vg, vb, vm, vv, sv, tv, Nn);

  for (int b0 = 0; b0 < Bb; b0 += G) {
    const float* xg   = x  + (size_t)b0 * Cc * Nn;
    float*       Vtg  = Vt + (size_t)b0 * Cc * Ee;
    float*       outg = (float*)d_out + (size_t)b0 * Cc * Nn;

    // Q[g,e,c] = sum_n Wq[e,n] * relu(s_q[n]*x[g,c,n]+t_q[n])
    gemm_nt<2><<<dim3(Cc / BNc, Ee / BM, G), blk, 0, stream>>>(
        Wq, xg, Q, Ee, Cc, Nn, 0L, (long)Cc * Nn, (long)Ee * Cc, sq, tq, 1.0f);
    // K[g,e,c]
    gemm_nt<2><<<dim3(Cc / BNc, Ee / BM, G), blk, 0, stream>>>(
        Wk, xg, Kb, Ee, Cc, Nn, 0L, (long)Cc * Nn, (long)Ee * Cc, sk, tk, 1.0f);
    // Vt[g,c,e] = sum_n relu(s_v[n]*x[g,c,n]+t_v[n]) * Wv[e,n]  (V transposed, in d_out)
    gemm_nt<1><<<dim3(Ee / BNc, Cc / BM, G), blk, 0, stream>>>(
        xg, Wv, Vtg, Cc, Ee, Nn, (long)Cc * Nn, 0L, (long)Cc * Ee, sv, tv, 1.0f);
    // S[g,e,f] = (1/32) * sum_c Q[g,e,c] * K[g,f,c]
    gemm_nt<0><<<dim3(Ee / BNc, Ee / BM, G), blk, 0, stream>>>(
        Q, Kb, S, Ee, Ee, Cc, (long)Ee * Cc, (long)Ee * Cc, (long)Ee * Ee,
        nullptr, nullptr, 0.03125f);
    // softmax over f (rows of 1024), in place
    softmax_rows<<<dim3(G * Ee), blk, 0, stream>>>(S);
    // Ot[g,c,e] = sum_f Vt[g,c,f] * P[g,e,f]   (overwrites Q chunk; Q dead after S)
    gemm_nt<0><<<dim3(Ee / BNc, Cc / BM, G), blk, 0, stream>>>(
        Vtg, S, Ot, Cc, Ee, Ee, (long)Cc * Ee, (long)Ee * Ee, (long)Cc * Ee,
        nullptr, nullptr, 1.0f);
    // out[g,c,n] = sum_e Ot[g,c,e] * Wp[n,e]  (overwrites Vt chunk; Vt dead after PV)
    gemm_nt<0><<<dim3(Nn / BNc, Cc / BM, G), blk, 0, stream>>>(
        Ot, Wp, outg, Cc, Nn, Ee, (long)Cc * Ee, 0L, (long)Cc * Nn,
        nullptr, nullptr, 1.0f);
  }
}

// Round 4
// 865.520 us; speedup vs baseline: 3.0668x; 3.0668x over previous
//
#include <hip/hip_runtime.h>
#include <math.h>

#define BN_EPS 1e-5f

namespace {

constexpr int Bb = 32;   // batch
constexpr int Cc = 512;  // channels
constexpr int Nn = 1024; // spatial (H*W)
constexpr int Ee = 1024; // embed

typedef __attribute__((ext_vector_type(8))) short short8;
typedef __attribute__((ext_vector_type(4))) float f32x4;
typedef __attribute__((ext_vector_type(4))) unsigned short ushort4_t;

struct bfpair { unsigned short h, l; };

__device__ __forceinline__ unsigned short bf16_rne(float v) {
  unsigned u = __builtin_bit_cast(unsigned, v);
  unsigned r = u + 0x7FFFu + ((u >> 16) & 1u);
  return (unsigned short)(r >> 16);
}
__device__ __forceinline__ float bf16_to_f(unsigned short h) {
  unsigned u = ((unsigned)h) << 16;
  return __builtin_bit_cast(float, u);
}
__device__ __forceinline__ bfpair split_bf(float v) {
  bfpair p;
  p.h = bf16_rne(v);
  p.l = bf16_rne(v - bf16_to_f(p.h));
  return p;
}

__device__ __forceinline__ void gll16(const void* g, void* l) {
  __builtin_amdgcn_global_load_lds(
      (const __attribute__((address_space(1))) void*)g,
      (__attribute__((address_space(3))) void*)l, 16, 0, 0);
}

__global__ __launch_bounds__(256) void prep_st_kernel(
    const float* __restrict__ g, const float* __restrict__ be,
    const float* __restrict__ mn, const float* __restrict__ vr,
    float* __restrict__ s, float* __restrict__ t, int n) {
  int i = blockIdx.x * blockDim.x + threadIdx.x;
  if (i < n) {
    float inv = rsqrtf(vr[i] + BN_EPS);
    float sc = g[i] * inv;
    s[i] = sc;
    t[i] = be[i] - mn[i] * sc;
  }
}

// y = relu(s[n]*x + t[n]) split to hi/lo bf16. x flat [G][C][N], N=1024.
__global__ __launch_bounds__(256) void convert_y(
    const float* __restrict__ x, const float* __restrict__ s, const float* __restrict__ tt,
    unsigned short* __restrict__ yh, unsigned short* __restrict__ yl, long total4) {
  for (long i = (long)blockIdx.x * 256 + threadIdx.x; i < total4; i += (long)gridDim.x * 256) {
    float4 v = ((const float4*)x)[i];
    int n4 = (int)(i & 255);  // N/4 = 256 float4 per row
    float4 s4 = ((const float4*)s)[n4];
    float4 t4 = ((const float4*)tt)[n4];
    float e0 = fmaxf(fmaf(v.x, s4.x, t4.x), 0.f);
    float e1 = fmaxf(fmaf(v.y, s4.y, t4.y), 0.f);
    float e2 = fmaxf(fmaf(v.z, s4.z, t4.z), 0.f);
    float e3 = fmaxf(fmaf(v.w, s4.w, t4.w), 0.f);
    bfpair p0 = split_bf(e0), p1 = split_bf(e1), p2 = split_bf(e2), p3 = split_bf(e3);
    ushort4_t hv, lv;
    hv.x = p0.h; hv.y = p1.h; hv.z = p2.h; hv.w = p3.h;
    lv.x = p0.l; lv.y = p1.l; lv.z = p2.l; lv.w = p3.l;
    *(ushort4_t*)&yh[i * 4] = hv;
    *(ushort4_t*)&yl[i * 4] = lv;
  }
}

// plain f32 -> hi/lo bf16 split (weights)
__global__ __launch_bounds__(256) void convert_w(
    const float* __restrict__ wsrc, unsigned short* __restrict__ wh,
    unsigned short* __restrict__ wl, long total4) {
  for (long i = (long)blockIdx.x * 256 + threadIdx.x; i < total4; i += (long)gridDim.x * 256) {
    float4 v = ((const float4*)wsrc)[i];
    bfpair p0 = split_bf(v.x), p1 = split_bf(v.y), p2 = split_bf(v.z), p3 = split_bf(v.w);
    ushort4_t hv, lv;
    hv.x = p0.h; hv.y = p1.h; hv.z = p2.h; hv.w = p3.h;
    lv.x = p0.l; lv.y = p1.l; lv.z = p2.l; lv.w = p3.l;
    *(ushort4_t*)&wh[i * 4] = hv;
    *(ushort4_t*)&wl[i * 4] = lv;
  }
}

// Split-bf16 NT GEMM: C[m][n] = alpha * sum_k A[m][k]*B[n][k], A=Ah+Al, B=Bh+Bl.
// 128x128 tile, BK=32, 256 threads (4 waves, 2x2 of 64x64), mfma 16x16x32 bf16.
// acc += Ah*Bh + Ah*Bl + Al*Bh  (Al*Bl dropped, O(eps^2)).
// SPLIT: epilogue writes Chi/Clo bf16 split; else writes f32 Cf.
template<bool SPLIT>
__global__ __launch_bounds__(256) void gemm3(
    const unsigned short* __restrict__ Ah, const unsigned short* __restrict__ Al,
    long ldA, long bsA,
    const unsigned short* __restrict__ Bh, const unsigned short* __restrict__ Bl,
    long ldB, long bsB,
    float* __restrict__ Cf, unsigned short* __restrict__ Chi, unsigned short* __restrict__ Clo,
    long ldC, long bsC, int K, float alpha) {
  __shared__ unsigned short sAh[128][32], sAl[128][32], sBh[128][32], sBl[128][32];

  const int t = threadIdx.x, lane = t & 63, w = t >> 6;
  const int m0 = blockIdx.y * 128, n0 = blockIdx.x * 128;
  const long zb = blockIdx.z;

  const int sr = lane >> 2;            // staging row within 16-row group
  const int sk = (lane & 3) * 8;       // staging k element offset
  const int wr = w >> 1, wc = w & 1;   // wave quadrant
  const int fr = lane & 15;            // fragment row/col
  const int kq = (lane >> 4) * 8;      // fragment k chunk (element offset)

  const unsigned short* a0 = Ah + zb * bsA + (long)(m0 + w * 32 + sr) * ldA + sk;
  const unsigned short* a1 = Al + zb * bsA + (long)(m0 + w * 32 + sr) * ldA + sk;
  const unsigned short* b0 = Bh + zb * bsB + (long)(n0 + w * 32 + sr) * ldB + sk;
  const unsigned short* b1 = Bl + zb * bsB + (long)(n0 + w * 32 + sr) * ldB + sk;
  const long a16 = 16 * ldA, b16 = 16 * ldB;

  f32x4 acc[4][4] = {};

  for (int k0 = 0; k0 < K; k0 += 32) {
    __syncthreads();  // previous tile fully consumed
    gll16(a0, &sAh[w * 32][0]);      gll16(a0 + a16, &sAh[w * 32 + 16][0]);
    gll16(a1, &sAl[w * 32][0]);      gll16(a1 + a16, &sAl[w * 32 + 16][0]);
    gll16(b0, &sBh[w * 32][0]);      gll16(b0 + b16, &sBh[w * 32 + 16][0]);
    gll16(b1, &sBl[w * 32][0]);      gll16(b1 + b16, &sBl[w * 32 + 16][0]);
    a0 += 32; a1 += 32; b0 += 32; b1 += 32;
    __syncthreads();  // staged data visible (compiler drains vmcnt before barrier)

    short8 ah[4], al[4], bh[4], bl[4];
#pragma unroll
    for (int i = 0; i < 4; ++i) {
      ah[i] = *(const short8*)&sAh[wr * 64 + i * 16 + fr][kq];
      al[i] = *(const short8*)&sAl[wr * 64 + i * 16 + fr][kq];
      bh[i] = *(const short8*)&sBh[wc * 64 + i * 16 + fr][kq];
      bl[i] = *(const short8*)&sBl[wc * 64 + i * 16 + fr][kq];
    }
#pragma unroll
    for (int i = 0; i < 4; ++i)
#pragma unroll
      for (int j = 0; j < 4; ++j) {
        acc[i][j] = __builtin_amdgcn_mfma_f32_16x16x32_bf16(ah[i], bh[j], acc[i][j], 0, 0, 0);
        acc[i][j] = __builtin_amdgcn_mfma_f32_16x16x32_bf16(ah[i], bl[j], acc[i][j], 0, 0, 0);
        acc[i][j] = __builtin_amdgcn_mfma_f32_16x16x32_bf16(al[i], bh[j], acc[i][j], 0, 0, 0);
      }
  }

  // epilogue: C/D layout col = lane&15, row = (lane>>4)*4 + reg  [verified m89/m91]
  const int rb = (lane >> 4) * 4;
#pragma unroll
  for (int i = 0; i < 4; ++i)
#pragma unroll
    for (int j = 0; j < 4; ++j) {
      long col = n0 + wc * 64 + j * 16 + fr;
#pragma unroll
      for (int v = 0; v < 4; ++v) {
        long row = m0 + wr * 64 + i * 16 + rb + v;
        float val = acc[i][j][v] * alpha;
        long idx = zb * bsC + row * ldC + col;
        if (SPLIT) {
          bfpair p = split_bf(val);
          Chi[idx] = p.h;
          Clo[idx] = p.l;
        } else {
          Cf[idx] = val;
        }
      }
    }
}

// softmax over rows of 1024 f32, writes P split as hi[1024]|lo[1024] ushorts in place.
__global__ __launch_bounds__(256) void softmax_rows(float* __restrict__ S) {
  long row = blockIdx.x;
  float* p = S + row * 1024;
  int t = threadIdx.x;
  float4 v = *(float4*)(p + 4 * t);
  float mx = fmaxf(fmaxf(v.x, v.y), fmaxf(v.z, v.w));
#pragma unroll
  for (int i = 1; i < 64; i <<= 1) mx = fmaxf(mx, __shfl_xor(mx, i));
  __shared__ float redm[4];
  __shared__ float reds[4];
  int wave = t >> 6, lane = t & 63;
  if (lane == 0) redm[wave] = mx;
  __syncthreads();
  mx = fmaxf(fmaxf(redm[0], redm[1]), fmaxf(redm[2], redm[3]));
  float e0 = expf(v.x - mx), e1 = expf(v.y - mx);
  float e2 = expf(v.z - mx), e3 = expf(v.w - mx);
  float sum = (e0 + e1) + (e2 + e3);
#pragma unroll
  for (int i = 1; i < 64; i <<= 1) sum += __shfl_xor(sum, i);
  if (lane == 0) reds[wave] = sum;
  __syncthreads();
  sum = (reds[0] + reds[1]) + (reds[2] + reds[3]);
  float inv = 1.0f / sum;
  bfpair p0 = split_bf(e0 * inv), p1 = split_bf(e1 * inv);
  bfpair p2 = split_bf(e2 * inv), p3 = split_bf(e3 * inv);
  ushort4_t hv, lv;
  hv.x = p0.h; hv.y = p1.h; hv.z = p2.h; hv.w = p3.h;
  lv.x = p0.l; lv.y = p1.l; lv.z = p2.l; lv.w = p3.l;
  unsigned short* ph = (unsigned short*)p;
  *(ushort4_t*)&ph[4 * t] = hv;          // hi: ushorts [0,1024)
  *(ushort4_t*)&ph[1024 + 4 * t] = lv;   // lo: ushorts [1024,2048)
}

}  // namespace

extern "C" void kernel_launch(void* const* d_in, const int* in_sizes, int n_in,
                              void* d_out, int out_size, void* d_ws, size_t ws_size,
                              hipStream_t stream) {
  const float* x  = (const float*)d_in[0];
  const float* qg = (const float*)d_in[1];
  const float* qb = (const float*)d_in[2];
  const float* qm = (const float*)d_in[3];
  const float* qv = (const float*)d_in[4];
  const float* kg = (const float*)d_in[5];
  const float* kb = (const float*)d_in[6];
  const float* km = (const float*)d_in[7];
  const float* kv = (const float*)d_in[8];
  const float* vg = (const float*)d_in[9];
  const float* vb = (const float*)d_in[10];
  const float* vm = (const float*)d_in[11];
  const float* vv = (const float*)d_in[12];
  const float* Wq = (const float*)d_in[13];
  const float* Wk = (const float*)d_in[14];
  const float* Wv = (const float*)d_in[15];
  const float* Wp = (const float*)d_in[16];

  // ---- workspace layout ----
  // header 64 KiB: BN scale/shift (6x1024 f32)
  // W hi/lo: 8 arrays of 1M ushort = 16 MiB
  // per batch: y hi/lo 2 MiB, Q hi/lo 2, K hi/lo 2, Vt hi/lo 2, S f32 4  => 12 MiB
  const size_t wMB = 8UL * 1024 * 1024 * 2;           // 16 MiB
  const size_t perB = 12UL * 1024 * 1024;             // 12 MiB
  int G = 32;
  while (G > 1 && 65536 + wMB + (size_t)G * perB > ws_size) G >>= 1;

  char* ws = (char*)d_ws;
  float* sq = (float*)ws;
  float* tq = sq + 1024;
  float* sk = tq + 1024;
  float* tk = sk + 1024;
  float* sv = tk + 1024;
  float* tv = sv + 1024;

  const long WE = 1024L * 1024;  // elements per weight matrix
  unsigned short* Wqh = (unsigned short*)(ws + 65536);
  unsigned short* Wql = Wqh + WE;
  unsigned short* Wkh = Wql + WE;
  unsigned short* Wkl = Wkh + WE;
  unsigned short* Wvh = Wkl + WE;
  unsigned short* Wvl = Wvh + WE;
  unsigned short* Wph = Wvl + WE;
  unsigned short* Wpl = Wph + WE;

  const long PB = (long)Cc * Ee;  // 524288: elements per batch of y/Q/K/Vt
  unsigned short* yh  = Wpl + WE;
  unsigned short* yl  = yh + (long)G * PB;
  unsigned short* Qh  = yl + (long)G * PB;
  unsigned short* Ql  = Qh + (long)G * PB;
  unsigned short* Kh  = Ql + (long)G * PB;
  unsigned short* Kl  = Kh + (long)G * PB;
  unsigned short* Vth = Kl + (long)G * PB;
  unsigned short* Vtl = Vth + (long)G * PB;
  float* S = (float*)(Vtl + (long)G * PB);           // [G][E][E] f32
  unsigned short* Oth = Qh;  // reuse Q (dead after S-GEMM)
  unsigned short* Otl = Ql;

  dim3 blk(256);

  prep_st_kernel<<<dim3(4), blk, 0, stream>>>(qg, qb, qm, qv, sq, tq, Nn);
  prep_st_kernel<<<dim3(4), blk, 0, stream>>>(kg, kb, km, kv, sk, tk, Nn);
  prep_st_kernel<<<dim3(4), blk, 0, stream>>>(vg, vb, vm, vv, sv, tv, Nn);

  const long W4 = WE / 4;
  convert_w<<<dim3(1024), blk, 0, stream>>>(Wq, Wqh, Wql, W4);
  convert_w<<<dim3(1024), blk, 0, stream>>>(Wk, Wkh, Wkl, W4);
  convert_w<<<dim3(1024), blk, 0, stream>>>(Wv, Wvh, Wvl, W4);
  convert_w<<<dim3(1024), blk, 0, stream>>>(Wp, Wph, Wpl, W4);

  const long y4 = (long)G * PB / 4;

  for (int b0 = 0; b0 < Bb; b0 += G) {
    const float* xg = x + (size_t)b0 * Cc * Nn;
    float* outg = (float*)d_out + (size_t)b0 * Cc * Nn;

    // ---- Q = Wq x BN_q(x):  M=E, N=C, K=Nn ----
    convert_y<<<dim3(2048), blk, 0, stream>>>(xg, sq, tq, yh, yl, y4);
    gemm3<true><<<dim3(Cc / 128, Ee / 128, G), blk, 0, stream>>>(
        Wqh, Wql, Nn, 0L, yh, yl, Nn, PB,
        nullptr, Qh, Ql, Cc, PB, Nn, 1.0f);
    // ---- K ----
    convert_y<<<dim3(2048), blk, 0, stream>>>(xg, sk, tk, yh, yl, y4);
    gemm3<true><<<dim3(Cc / 128, Ee / 128, G), blk, 0, stream>>>(
        Wkh, Wkl, Nn, 0L, yh, yl, Nn, PB,
        nullptr, Kh, Kl, Cc, PB, Nn, 1.0f);
    // ---- Vt = BN_v(x) x Wv^T: M=C, N=E, K=Nn (transposed V) ----
    convert_y<<<dim3(2048), blk, 0, stream>>>(xg, sv, tv, yh, yl, y4);
    gemm3<true><<<dim3(Ee / 128, Cc / 128, G), blk, 0, stream>>>(
        yh, yl, Nn, PB, Wvh, Wvl, Nn, 0L,
        nullptr, Vth, Vtl, Ee, PB, Nn, 1.0f);
    // ---- S = Q K^T / 32: M=E, N=E, K=C, f32 out ----
    gemm3<false><<<dim3(Ee / 128, Ee / 128, G), blk, 0, stream>>>(
        Qh, Ql, Cc, PB, Kh, Kl, Cc, PB,
        S, nullptr, nullptr, Ee, (long)Ee * Ee, Cc, 0.03125f);
    // ---- softmax rows -> P hi/lo packed in S ----
    softmax_rows<<<dim3(G * Ee), blk, 0, stream>>>(S);
    // ---- Ot = Vt x P^T: M=C, N=E, K=E (P rows are k-contig) ----
    gemm3<true><<<dim3(Ee / 128, Cc / 128, G), blk, 0, stream>>>(
        Vth, Vtl, Ee, PB, (unsigned short*)S, (unsigned short*)S + 1024,
        2L * Ee, 2L * Ee * Ee,
        nullptr, Oth, Otl, Ee, PB, Ee, 1.0f);
    // ---- out = Ot x Wp^T: M=C, N=Nn, K=E, f32 out to d_out ----
    gemm3<false><<<dim3(Nn / 128, Cc / 128, G), blk, 0, stream>>>(
        Oth, Otl, Ee, PB, Wph, Wpl, Ee, 0L,
        outg, nullptr, nullptr, Nn, (long)Cc * Nn, Ee, 1.0f);
  }
}